// Round 11
// baseline (1614.370 us; speedup 1.0000x reference)
//
#include <hip/hip_runtime.h>
#include <hip/hip_bf16.h>
#include <cstdint>
#include <type_traits>

#define T_DIM 1024
#define B_DIM 64
#define IN_DIM 32
#define EMB_DIM 64
#define HID_DIM 128
#define K_TAPS 16
#define OUT_DIM 32
#define G4 (4*HID_DIM)          // 512 packed gates [i,o,c,d]
#define MROWS (T_DIM*B_DIM)     // 65536

typedef _Float16 half8 __attribute__((ext_vector_type(8)));
typedef _Float16 half4 __attribute__((ext_vector_type(4)));
typedef float f32x4 __attribute__((ext_vector_type(4)));

#define MFMA16(a,b,c) __builtin_amdgcn_mfma_f32_16x16x32_f16((a),(b),(c),0,0,0)

// fast sigmoid/tanh via v_exp_f32 + v_rcp_f32 (rel err ~1e-6)
__device__ __forceinline__ float fast_sigmoid(float x) {
    return __builtin_amdgcn_rcpf(1.0f + __expf(-x));
}
__device__ __forceinline__ float fast_tanh(float x) {
    return 1.0f - 2.0f * __builtin_amdgcn_rcpf(1.0f + __expf(2.0f * x));
}

// Raw per-step barrier: LDS visibility only — does NOT drain vmcnt, so the
// xg prefetch loads and Hout stores stay in flight across steps (the
// __syncthreads() vmcnt(0) drain was ~2x the step time in R9's 1507 cyc/step).
__device__ __forceinline__ void step_barrier() {
    __builtin_amdgcn_sched_barrier(0);
    asm volatile("s_waitcnt lgkmcnt(0)" ::: "memory");
    __builtin_amdgcn_s_barrier();
    __builtin_amdgcn_sched_barrier(0);
}

// ---------------------------------------------------------------------------
// Small weight-combine GEMM: C[M2 x 512] = A[M2 x K2] @ Bm[K2 x 512]
__global__ void gemm_small(const float* __restrict__ A, const float* __restrict__ Bm,
                           float* __restrict__ C, int K2)
{
    int i = blockIdx.x, j = threadIdx.x;
    float acc = 0.f;
    for (int k = 0; k < K2; ++k) acc += A[i * K2 + k] * Bm[k * G4 + j];
    C[i * G4 + j] = acc;
}

__global__ void bias_comb(const float* __restrict__ bvec, const float* __restrict__ Bm,
                          const float* __restrict__ badd, float* __restrict__ bc, int K2)
{
    int j = threadIdx.x;
    float acc = badd[j];
    for (int k = 0; k < K2; ++k) acc += bvec[k] * Bm[k * G4 + j];
    bc[j] = acc;
}

// ---------------------------------------------------------------------------
// MFMA GEMM: C[M x NSTR](f32) = A[M x KK](TA) @ W[KK x NSTR](f32, cvt f16) + bias
template<int KK, int NCOLS, int NSTR, typename TA>
__global__ __launch_bounds__(256) void gemm_mfma(
    const TA* __restrict__ A, const float* __restrict__ W,
    const float* __restrict__ bias, float* __restrict__ C)
{
    constexpr int KT = KK / 32;      // K-tiles
    constexpr int NT = NCOLS / 16;   // N-tiles per wave
    const int bm = blockIdx.x, bn = blockIdx.y;
    const int tid = threadIdx.x;
    const int w = tid >> 6, l = tid & 63, lc = l & 15, lk = l >> 4;

    __shared__ __align__(16) _Float16 aLds[64][KK + 8];

    if constexpr (std::is_same_v<TA, float>) {
        const float* Ab = A + (size_t)bm * 64 * KK;
        for (int idx = tid * 4; idx < 64 * KK; idx += 1024) {
            const int r = idx / KK, k = idx % KK;
            float4 v = *(const float4*)&Ab[idx];
            half4 h; h[0] = (_Float16)v.x; h[1] = (_Float16)v.y;
            h[2] = (_Float16)v.z; h[3] = (_Float16)v.w;
            *(half4*)&aLds[r][k] = h;
        }
    } else {
        const _Float16* Ab = (const _Float16*)A + (size_t)bm * 64 * KK;
        for (int idx = tid * 8; idx < 64 * KK; idx += 2048) {
            const int r = idx / KK, k = idx % KK;
            *(half8*)&aLds[r][k] = *(const half8*)&Ab[idx];
        }
    }

    half8 bf[NT][KT];
#pragma unroll
    for (int nt = 0; nt < NT; ++nt)
#pragma unroll
        for (int kt = 0; kt < KT; ++kt) {
            half8 v;
#pragma unroll
            for (int e = 0; e < 8; ++e)
                v[e] = (_Float16)W[(size_t)(kt * 32 + lk * 8 + e) * NSTR + bn * NCOLS + nt * 16 + lc];
            bf[nt][kt] = v;
        }

    __syncthreads();

    half8 af[KT];
#pragma unroll
    for (int kt = 0; kt < KT; ++kt)
        af[kt] = *(const half8*)&aLds[w * 16 + lc][kt * 32 + lk * 8];

    f32x4 acc[NT];
#pragma unroll
    for (int nt = 0; nt < NT; ++nt) acc[nt] = (f32x4){0.f, 0.f, 0.f, 0.f};
#pragma unroll
    for (int nt = 0; nt < NT; ++nt)
#pragma unroll
        for (int kt = 0; kt < KT; ++kt)
            acc[nt] = MFMA16(af[kt], bf[nt][kt], acc[nt]);

#pragma unroll
    for (int nt = 0; nt < NT; ++nt) {
        const int col = bn * NCOLS + nt * 16 + lc;
        const float bv = bias[col];
#pragma unroll
        for (int r = 0; r < 4; ++r) {
            const int row = bm * 64 + w * 16 + lk * 4 + r;
            C[(size_t)row * NSTR + col] = acc[nt][r] + bv;
        }
    }
}

// ---------------------------------------------------------------------------
// Recurrent scan, MFMA matvec with stride-0 A-broadcast trick.
// 16 INDEPENDENT zero-C MFMAs per step (no C-chains) + VALU tree-add.
// Raw lgkmcnt-only barrier; 4-deep xg prefetch (slot p&3, static idx).
__global__ __launch_bounds__(512, 2) void scan_kernel(
    const float* __restrict__ XG, const float* __restrict__ Wh,
    _Float16* __restrict__ HoutH)
{
    const int b = blockIdx.x;
    const int tid = threadIdx.x;
    const int w = tid >> 6, l = tid & 63, lc = l & 15, lk = l >> 4;
    const int hid = w * 16 + lc;

    __shared__ __align__(16) _Float16 hbuf[2][HID_DIM];

    // B-frags: Wh[k][col], col = gt*128 + hid, k = kt*32 + lk*8 + e  (64 VGPR)
    half8 bf[4][4];
#pragma unroll
    for (int gt = 0; gt < 4; ++gt)
#pragma unroll
        for (int kt = 0; kt < 4; ++kt) {
            half8 v;
#pragma unroll
            for (int e = 0; e < 8; ++e)
                v[e] = (_Float16)Wh[(size_t)(kt * 32 + lk * 8 + e) * G4 + gt * 128 + hid];
            bf[gt][kt] = v;
        }

    float rb[K_TAPS];
#pragma unroll
    for (int p = 0; p < K_TAPS; ++p) rb[p] = 0.f;

    if (tid < HID_DIM) { hbuf[0][tid] = (_Float16)0.f; hbuf[1][tid] = (_Float16)0.f; }
    __syncthreads();

    const float* xgb = XG + (size_t)b * G4;
    float xgp[4][4];                    // [slot][gate], 4-deep prefetch
#pragma unroll
    for (int s = 0; s < 4; ++s)
#pragma unroll
        for (int gt = 0; gt < 4; ++gt)
            xgp[s][gt] = xgb[(size_t)s * (B_DIM * G4) + gt * 128 + hid];

    for (int tb = 0; tb < T_DIM; tb += K_TAPS) {
#pragma unroll
        for (int p = 0; p < K_TAPS; ++p) {
            const int t = tb + p;
            // ---- A-frags: stride-0 rows -> 4 broadcast b128 reads
            half8 af0 = *(const half8*)&hbuf[p & 1][ 0 + lk * 8];
            half8 af1 = *(const half8*)&hbuf[p & 1][32 + lk * 8];
            half8 af2 = *(const half8*)&hbuf[p & 1][64 + lk * 8];
            half8 af3 = *(const half8*)&hbuf[p & 1][96 + lk * 8];

            // ---- 16 independent MFMAs (zero C), then tree-add element [0]
            const f32x4 z = (f32x4){0.f, 0.f, 0.f, 0.f};
            f32x4 q[4][4];
#pragma unroll
            for (int gt = 0; gt < 4; ++gt) {
                q[gt][0] = MFMA16(af0, bf[gt][0], z);
                q[gt][1] = MFMA16(af1, bf[gt][1], z);
                q[gt][2] = MFMA16(af2, bf[gt][2], z);
                q[gt][3] = MFMA16(af3, bf[gt][3], z);
            }
            const float gi = xgp[p & 3][0] + ((q[0][0][0] + q[0][1][0]) + (q[0][2][0] + q[0][3][0]));
            const float go = xgp[p & 3][1] + ((q[1][0][0] + q[1][1][0]) + (q[1][2][0] + q[1][3][0]));
            const float gc = xgp[p & 3][2] + ((q[2][0][0] + q[2][1][0]) + (q[2][2][0] + q[2][3][0]));
            const float gd = xgp[p & 3][3] + ((q[3][0][0] + q[3][1][0]) + (q[3][2][0] + q[3][3][0]));

            // ---- prefetch xg for t+4 into the slot just consumed
            if (t + 4 < T_DIM) {
#pragma unroll
                for (int gt = 0; gt < 4; ++gt)
                    xgp[p & 3][gt] = xgb[(size_t)(t + 4) * (B_DIM * G4) + gt * 128 + hid];
            }

            // ---- pointwise + fractional filter (serial wj chain, tree c-sum)
            const float ig = fast_sigmoid(gi);
            const float og = fast_sigmoid(go);
            const float d  = 0.5f * fast_sigmoid(gd);
            const float hc = ig * fast_tanh(gc);
            rb[p] = hc;

            float term[K_TAPS];
            term[0] = hc;
            float wprod = 1.f;
#pragma unroll
            for (int jj = 1; jj < K_TAPS; ++jj) {
                wprod *= (jj - 1.0f + d) * (1.0f / jj);
                term[jj] = wprod * rb[(p - jj) & (K_TAPS - 1)];
            }
            float s01 = (term[0] + term[1])   + (term[2] + term[3]);
            float s23 = (term[4] + term[5])   + (term[6] + term[7]);
            float s45 = (term[8] + term[9])   + (term[10] + term[11]);
            float s67 = (term[12] + term[13]) + (term[14] + term[15]);
            const float c = (s01 + s23) + (s45 + s67);

            const float hn = og * fast_tanh(c);

            if (lk == 0) {
                hbuf[(p & 1) ^ 1][hid] = (_Float16)hn;
                HoutH[(size_t)t * (B_DIM * HID_DIM) + b * HID_DIM + hid] = (_Float16)hn;
            }
            step_barrier();   // LDS-only wait: h(t) visible, reads of hbuf[p&1] done
        }
    }
}

// ---------------------------------------------------------------------------
extern "C" void kernel_launch(void* const* d_in, const int* in_sizes, int n_in,
                              void* d_out, int out_size, void* d_ws, size_t ws_size,
                              hipStream_t stream)
{
    const float* inputs = (const float*)d_in[0];   // [T,B,32]
    const float* W_emb  = (const float*)d_in[1];   // [32,64]
    const float* b_emb  = (const float*)d_in[2];   // [64]
    const float* Wx0    = (const float*)d_in[3];   // [64,512]
    const float* Wh0    = (const float*)d_in[4];   // [128,512]
    const float* b0     = (const float*)d_in[5];   // [512]
    const float* Wo0    = (const float*)d_in[6];   // [128,128]
    const float* bo0    = (const float*)d_in[7];   // [128]
    const float* Wx1    = (const float*)d_in[8];   // [128,512]
    const float* Wh1    = (const float*)d_in[9];   // [128,512]
    const float* b1     = (const float*)d_in[10];  // [512]
    const float* Wo1    = (const float*)d_in[11];  // [128,32]
    const float* bo1    = (const float*)d_in[12];  // [32]
    float* out = (float*)d_out;

    float* ws = (float*)d_ws;
    float*     XG    = ws;                                          // 65536*512 f32
    _Float16*  HoutH = (_Float16*)(ws + (size_t)MROWS * G4);        // 65536*128 f16
    float*     W0c   = (float*)((char*)HoutH + (size_t)MROWS * HID_DIM * sizeof(_Float16));
    float*     b0c   = W0c + IN_DIM * G4;
    float*     W1c   = b0c + G4;
    float*     b1c   = W1c + HID_DIM * G4;

    // ---- layer 0: collapse embedding into Wx0 ----
    gemm_small<<<IN_DIM, G4, 0, stream>>>(W_emb, Wx0, W0c, EMB_DIM);
    bias_comb<<<1, G4, 0, stream>>>(b_emb, Wx0, b0, b0c, EMB_DIM);
    gemm_mfma<IN_DIM, 64, G4, float>
        <<<dim3(MROWS / 64, G4 / 64), 256, 0, stream>>>(inputs, W0c, b0c, XG);
    scan_kernel<<<B_DIM, 512, 0, stream>>>(XG, Wh0, HoutH);

    // ---- layer 1: collapse Wo0 into Wx1 ----
    gemm_small<<<HID_DIM, G4, 0, stream>>>(Wo0, Wx1, W1c, HID_DIM);
    bias_comb<<<1, G4, 0, stream>>>(bo0, Wx1, b1, b1c, HID_DIM);
    gemm_mfma<HID_DIM, 64, G4, _Float16>
        <<<dim3(MROWS / 64, G4 / 64), 256, 0, stream>>>(HoutH, W1c, b1c, XG);
    scan_kernel<<<B_DIM, 512, 0, stream>>>(XG, Wh1, HoutH);

    // ---- output projection (f16 MFMA, N=32) ----
    gemm_mfma<HID_DIM, OUT_DIM, OUT_DIM, _Float16>
        <<<dim3(MROWS / 64, 1), 256, 0, stream>>>(HoutH, Wo1, bo1, out);
}